// Round 1
// baseline (2046.562 us; speedup 1.0000x reference)
//
#include <hip/hip_runtime.h>
#include <math.h>

#define N_NODES 15000
#define N_EDGES 40000
#define N_GRAPHS 750

__device__ __forceinline__ float sigmoidf_(float x) { return 1.f / (1.f + expf(-x)); }

// ---------------- prep kernels ----------------
__global__ void count_kernel(const int* __restrict__ src, const int* __restrict__ dst,
                             int* __restrict__ cnt, float* __restrict__ deg) {
    int e = blockIdx.x * 256 + threadIdx.x;
    if (e >= N_EDGES) return;
    atomicAdd(&cnt[src[e]], 1);
    atomicAdd(&deg[dst[e]], 1.f);
}

__global__ void scan_kernel(const int* __restrict__ cnt, int* __restrict__ src_ptr,
                            int* __restrict__ cursor) {
    __shared__ int buf[1024];
    __shared__ int carry_s;
    int t = threadIdx.x;
    if (t == 0) carry_s = 0;
    __syncthreads();
    for (int base = 0; base < N_NODES; base += 1024) {
        int carry = carry_s;
        int i = base + t;
        int v = (i < N_NODES) ? cnt[i] : 0;
        buf[t] = v;
        __syncthreads();
        for (int ofs = 1; ofs < 1024; ofs <<= 1) {
            int add = (t >= ofs) ? buf[t - ofs] : 0;
            __syncthreads();
            buf[t] += add;
            __syncthreads();
        }
        int incl = buf[t];
        int excl = incl - v + carry;
        if (i < N_NODES) { src_ptr[i] = excl; cursor[i] = excl; }
        __syncthreads();
        if (t == 1023) carry_s = carry + incl;
        __syncthreads();
    }
    if (t == 0) src_ptr[N_NODES] = carry_s;
}

__global__ void fill_kernel(const int* __restrict__ src, int* __restrict__ cursor,
                            int* __restrict__ edge_list) {
    int e = blockIdx.x * 256 + threadIdx.x;
    if (e >= N_EDGES) return;
    int slot = atomicAdd(&cursor[src[e]], 1);
    edge_list[slot] = e;
}

__global__ void gptr_kernel(const int* __restrict__ batch, int* __restrict__ gptr) {
    int n = blockIdx.x * 256 + threadIdx.x;
    if (n >= N_NODES) return;
    int b = batch[n];
    int pb = (n == 0) ? -1 : batch[n - 1];
    for (int g = pb + 1; g <= b; ++g) gptr[g] = n;
    if (n == N_NODES - 1)
        for (int g = b + 1; g <= N_GRAPHS; ++g) gptr[g] = N_NODES;
}

__global__ void proj_kernel(const float* __restrict__ x, const float* __restrict__ W,
                            const float* __restrict__ b, float* __restrict__ node_h) {
    int idx = blockIdx.x * 256 + threadIdx.x;
    if (idx >= N_NODES * 64) return;
    int n = idx >> 6, f = idx & 63;
    float s = b[f];
    #pragma unroll
    for (int i = 0; i < 32; ++i) s += x[n * 32 + i] * W[i * 64 + f];
    node_h[idx] = fmaxf(s, 0.f);
}

__global__ void h1_kernel(const float* __restrict__ ea, const float* __restrict__ W,
                          const float* __restrict__ b, float* __restrict__ h1) {
    int idx = blockIdx.x * 256 + threadIdx.x;
    if (idx >= N_EDGES * 64) return;
    int e = idx >> 6, f = idx & 63;
    float s = b[f];
    #pragma unroll
    for (int i = 0; i < 16; ++i) s += ea[e * 16 + i] * W[i * 64 + f];
    h1[idx] = fmaxf(s, 0.f);
}

// ---------------- fused conv: per-node T-tile + message scatter ----------------
// Grid: 938 node-tiles (16 nodes) x 8 f-tiles (8 f each). Block 256 threads.
// Phase A: T[n,k,f] = sum_d out[n,d]*e2W[k, d*64+f] into LDS (reg tile 8n x 4(kf)).
// Phase B: per out-edge of tile nodes: msg = Tb + sum_k h1[e,k]*T[n,k,f] -> atomicAdd agg[dst].
__global__ __launch_bounds__(256, 4)
void conv_kernel(const float* __restrict__ node_h, const float* __restrict__ h1,
                 const float* __restrict__ e2W, const float* __restrict__ e2b,
                 const int* __restrict__ src_ptr, const int* __restrict__ edge_list,
                 const int* __restrict__ dst, float* __restrict__ agg) {
    __shared__ float T_lds[16][520];   // [node][k*8+fi], row padded 512->520
    __shared__ float Tb[16][8];        // bias term: sum_d out[n,d]*e2b[d*64+f]
    int bid = blockIdx.x;
    int nt = bid >> 3, ft = bid & 7;
    int n0 = nt * 16, f0 = ft * 8;
    int tid = threadIdx.x;
    int pn = tid >> 7;                 // node half (0/1)
    int pp = tid & 127;
    int k = pp >> 1;
    int fo = (pp & 1) * 4;             // this thread's 4 f's within the 8-wide tile
    const float* Bp = e2W + (size_t)k * 4096 + f0 + fo;
    int nb = n0 + pn * 8;

    float acc[8][4];
    #pragma unroll
    for (int a = 0; a < 8; ++a)
        #pragma unroll
        for (int b = 0; b < 4; ++b) acc[a][b] = 0.f;

    for (int d4 = 0; d4 < 64; d4 += 4) {
        float4 A[8];
        #pragma unroll
        for (int nn = 0; nn < 8; ++nn) {
            int n = nb + nn;
            A[nn] = (n < N_NODES) ? *(const float4*)(node_h + (size_t)n * 64 + d4)
                                  : make_float4(0.f, 0.f, 0.f, 0.f);
        }
        #pragma unroll
        for (int dd = 0; dd < 4; ++dd) {
            float4 b4 = *(const float4*)(Bp + (size_t)(d4 + dd) * 64);
            float bv[4] = {b4.x, b4.y, b4.z, b4.w};
            #pragma unroll
            for (int nn = 0; nn < 8; ++nn) {
                float a = (&A[nn].x)[dd];
                #pragma unroll
                for (int j = 0; j < 4; ++j) acc[nn][j] += a * bv[j];
            }
        }
    }
    #pragma unroll
    for (int nn = 0; nn < 8; ++nn) {
        float4 v = make_float4(acc[nn][0], acc[nn][1], acc[nn][2], acc[nn][3]);
        *(float4*)(&T_lds[pn * 8 + nn][pp * 4]) = v;  // p = k*8 + fi == pp*4+j
    }
    if (tid < 128) {  // 16 nodes x 8 f bias terms
        int nn = tid >> 3, fi = tid & 7;
        int n = n0 + nn;
        float s = 0.f;
        if (n < N_NODES) {
            for (int d = 0; d < 64; ++d) s += node_h[(size_t)n * 64 + d] * e2b[d * 64 + f0 + fi];
        }
        Tb[nn][fi] = s;
    }
    __syncthreads();

    int fi = tid & 7, slot = tid >> 3;  // 32 edge slots x 8 f
    for (int nn = 0; nn < 16; ++nn) {
        int n = n0 + nn;
        if (n >= N_NODES) break;
        int eb = src_ptr[n], ee = src_ptr[n + 1];
        for (int c = eb + slot; c < ee; c += 32) {
            int e = edge_list[c];
            const float* h1e = h1 + (size_t)e * 64;
            const float* Tr = &T_lds[nn][fi];
            float s = Tb[nn][fi];
            #pragma unroll 8
            for (int kk = 0; kk < 64; ++kk) s += h1e[kk] * Tr[kk * 8];
            atomicAdd(&agg[(size_t)dst[e] * 64 + f0 + fi], s);
        }
    }
}

// ---------------- GRU: weights register-resident, one node per block-iter ----------------
__global__ __launch_bounds__(192)
void gru_kernel(float* __restrict__ node_h, const float* __restrict__ agg,
                const float* __restrict__ deg, const float* __restrict__ conv_b,
                const float* __restrict__ Wih, const float* __restrict__ Whh,
                const float* __restrict__ bih, const float* __restrict__ bhh) {
    __shared__ float m_s[64], h_s[64], gi_s[192], gh_s[192];
    int j = threadIdx.x;  // 0..191 (gate-row)
    float wih[64], whh[64];
    #pragma unroll
    for (int i = 0; i < 64; i += 4) {
        float4 a = *(const float4*)(Wih + (size_t)j * 64 + i);
        wih[i] = a.x; wih[i + 1] = a.y; wih[i + 2] = a.z; wih[i + 3] = a.w;
        float4 c = *(const float4*)(Whh + (size_t)j * 64 + i);
        whh[i] = c.x; whh[i + 1] = c.y; whh[i + 2] = c.z; whh[i + 3] = c.w;
    }
    float bi = bih[j], bh = bhh[j];
    for (int n = blockIdx.x; n < N_NODES; n += gridDim.x) {
        if (j < 64) {
            float dg = fmaxf(deg[n], 1.f);
            m_s[j] = fmaxf(agg[(size_t)n * 64 + j] / dg + conv_b[j], 0.f);
            h_s[j] = node_h[(size_t)n * 64 + j];
        }
        __syncthreads();
        float gi = bi, gh = bh;
        #pragma unroll
        for (int d = 0; d < 64; ++d) { gi += m_s[d] * wih[d]; gh += h_s[d] * whh[d]; }
        gi_s[j] = gi; gh_s[j] = gh;
        __syncthreads();
        if (j < 64) {
            float r = sigmoidf_(gi_s[j] + gh_s[j]);
            float z = sigmoidf_(gi_s[j + 64] + gh_s[j + 64]);
            float nn = tanhf(gi_s[j + 128] + r * gh_s[j + 128]);
            node_h[(size_t)n * 64 + j] = (1.f - z) * nn + z * h_s[j];
        }
        __syncthreads();
    }
}

// ---------------- Set2Set step: LSTM + online-softmax attention, block per graph ----------------
__global__ __launch_bounds__(64)
void s2s_kernel(const float* __restrict__ node_h, const int* __restrict__ gptr,
                float* __restrict__ hl, float* __restrict__ cl, float* __restrict__ q_star,
                const float* __restrict__ Wih, const float* __restrict__ Whh,
                const float* __restrict__ bih, const float* __restrict__ bhh) {
    int g = blockIdx.x, t = threadIdx.x;
    __shared__ float qs[128], hs[64], q[64], wts[64];
    qs[t] = q_star[g * 128 + t];
    qs[64 + t] = q_star[g * 128 + 64 + t];
    hs[t] = hl[g * 64 + t];
    __syncthreads();
    float gv[4];
    #pragma unroll
    for (int gate = 0; gate < 4; ++gate) {
        int row = gate * 64 + t;
        float s = bih[row] + bhh[row];
        const float* wi = Wih + (size_t)row * 128;
        #pragma unroll 8
        for (int i = 0; i < 128; ++i) s += qs[i] * wi[i];
        const float* wh = Whh + (size_t)row * 64;
        #pragma unroll 8
        for (int i = 0; i < 64; ++i) s += hs[i] * wh[i];
        gv[gate] = s;
    }
    float c = sigmoidf_(gv[1]) * cl[g * 64 + t] + sigmoidf_(gv[0]) * tanhf(gv[2]);
    float hn = sigmoidf_(gv[3]) * tanhf(c);
    cl[g * 64 + t] = c;
    hl[g * 64 + t] = hn;
    q[t] = hn;
    __syncthreads();
    int nbeg = gptr[g], nend = gptr[g + 1];
    float rm = -INFINITY, rs = 0.f, racc = 0.f;
    for (int base = nbeg; base < nend; base += 64) {
        int n = base + t;
        float e = -INFINITY;
        if (n < nend) {
            float s = 0.f;
            #pragma unroll 8
            for (int f = 0; f < 64; ++f) s += node_h[(size_t)n * 64 + f] * q[f];
            e = s;
        }
        float cm = e;
        #pragma unroll
        for (int o = 32; o > 0; o >>= 1) cm = fmaxf(cm, __shfl_down(cm, o));
        cm = __shfl(cm, 0);
        float nm = fmaxf(rm, cm);
        float scale = (rm == -INFINITY) ? 0.f : expf(rm - nm);
        float wv = (n < nend) ? expf(e - nm) : 0.f;
        float cs = wv;
        #pragma unroll
        for (int o = 32; o > 0; o >>= 1) cs += __shfl_down(cs, o);
        cs = __shfl(cs, 0);
        wts[t] = wv;
        __syncthreads();
        float na = racc * scale;
        int cnt2 = min(64, nend - base);
        for (int l = 0; l < cnt2; ++l) na += wts[l] * node_h[(size_t)(base + l) * 64 + t];
        racc = na;
        rs = rs * scale + cs;
        rm = nm;
        __syncthreads();
    }
    float r = (nend > nbeg) ? racc / rs : 0.f;
    q_star[g * 128 + t] = q[t];
    q_star[g * 128 + 64 + t] = r;
}

// ---------------- output MLP ----------------
__global__ __launch_bounds__(128)
void out_kernel(const float* __restrict__ q_star, const float* __restrict__ W1,
                const float* __restrict__ b1, const float* __restrict__ W2,
                const float* __restrict__ b2, float* __restrict__ z) {
    int g = blockIdx.x, j = threadIdx.x;
    __shared__ float qs[128], red[128];
    qs[j] = q_star[g * 128 + j];
    __syncthreads();
    float s = b1[j];
    #pragma unroll 8
    for (int i = 0; i < 128; ++i) s += qs[i] * W1[i * 128 + j];
    red[j] = fmaxf(s, 0.f) * W2[j];
    __syncthreads();
    for (int o = 64; o > 0; o >>= 1) {
        if (j < o) red[j] += red[j + o];
        __syncthreads();
    }
    if (j == 0) z[g] = red[0] + b2[0];
}

extern "C" void kernel_launch(void* const* d_in, const int* in_sizes, int n_in,
                              void* d_out, int out_size, void* d_ws, size_t ws_size,
                              hipStream_t stream) {
    const float* x         = (const float*)d_in[0];
    const float* edge_attr = (const float*)d_in[1];
    const int*   ei        = (const int*)d_in[2];
    const int*   batch     = (const int*)d_in[3];
    const float* in_W      = (const float*)d_in[4];
    const float* in_b      = (const float*)d_in[5];
    const float* e1_W      = (const float*)d_in[6];
    const float* e1_b      = (const float*)d_in[7];
    const float* e2_W      = (const float*)d_in[8];
    const float* e2_b      = (const float*)d_in[9];
    const float* conv_b    = (const float*)d_in[10];
    const float* gWih      = (const float*)d_in[11];
    const float* gWhh      = (const float*)d_in[12];
    const float* gbih      = (const float*)d_in[13];
    const float* gbhh      = (const float*)d_in[14];
    const float* lWih      = (const float*)d_in[15];
    const float* lWhh      = (const float*)d_in[16];
    const float* lbih      = (const float*)d_in[17];
    const float* lbhh      = (const float*)d_in[18];
    const float* o1W       = (const float*)d_in[19];
    const float* o1b       = (const float*)d_in[20];
    const float* o2W       = (const float*)d_in[21];
    const float* o2b       = (const float*)d_in[22];
    const int* src = ei;
    const int* dst = ei + N_EDGES;
    float* z = (float*)d_out;

    char* ws = (char*)d_ws;
    size_t off = 0;
    auto alloc = [&](size_t bytes) {
        void* p = ws + off;
        off = (off + bytes + 255) & ~(size_t)255;
        return p;
    };
    float* node_h   = (float*)alloc((size_t)N_NODES * 64 * 4);
    float* agg      = (float*)alloc((size_t)N_NODES * 64 * 4);
    float* h1       = (float*)alloc((size_t)N_EDGES * 64 * 4);
    float* deg      = (float*)alloc(N_NODES * 4);       // deg,cnt adjacent (one memset)
    int*   cnt      = (int*)alloc(N_NODES * 4);
    int*   cursor   = (int*)alloc(N_NODES * 4);
    int*   src_ptr  = (int*)alloc((N_NODES + 1) * 4);
    int*   edge_list= (int*)alloc(N_EDGES * 4);
    int*   gptr     = (int*)alloc((N_GRAPHS + 1) * 4);
    float* hl       = (float*)alloc(N_GRAPHS * 64 * 4); // hl,cl,q_star adjacent (one memset)
    float* cl       = (float*)alloc(N_GRAPHS * 64 * 4);
    float* q_star   = (float*)alloc(N_GRAPHS * 128 * 4);

    size_t degpad = ((size_t)N_NODES * 4 + 255) & ~(size_t)255;
    hipMemsetAsync(deg, 0, degpad + (size_t)N_NODES * 4, stream);           // deg + cnt
    hipMemsetAsync(hl, 0, (size_t)N_GRAPHS * (64 + 64 + 128) * 4, stream);  // hl + cl + q_star

    count_kernel<<<(N_EDGES + 255) / 256, 256, 0, stream>>>(src, dst, cnt, deg);
    scan_kernel<<<1, 1024, 0, stream>>>(cnt, src_ptr, cursor);
    fill_kernel<<<(N_EDGES + 255) / 256, 256, 0, stream>>>(src, cursor, edge_list);
    gptr_kernel<<<(N_NODES + 255) / 256, 256, 0, stream>>>(batch, gptr);
    proj_kernel<<<(N_NODES * 64 + 255) / 256, 256, 0, stream>>>(x, in_W, in_b, node_h);
    h1_kernel<<<(N_EDGES * 64 + 255) / 256, 256, 0, stream>>>(edge_attr, e1_W, e1_b, h1);

    for (int it = 0; it < 3; ++it) {
        hipMemsetAsync(agg, 0, (size_t)N_NODES * 64 * 4, stream);
        conv_kernel<<<938 * 8, 256, 0, stream>>>(node_h, h1, e2_W, e2_b,
                                                 src_ptr, edge_list, dst, agg);
        gru_kernel<<<512, 192, 0, stream>>>(node_h, agg, deg, conv_b, gWih, gWhh, gbih, gbhh);
    }
    for (int st = 0; st < 3; ++st)
        s2s_kernel<<<N_GRAPHS, 64, 0, stream>>>(node_h, gptr, hl, cl, q_star,
                                                lWih, lWhh, lbih, lbhh);
    out_kernel<<<N_GRAPHS, 128, 0, stream>>>(q_star, o1W, o1b, o2W, o2b, z);
}

// Round 2
// 1245.910 us; speedup vs baseline: 1.6426x; 1.6426x over previous
//
#include <hip/hip_runtime.h>
#include <math.h>

#define N_NODES 15000
#define N_EDGES 40000
#define N_GRAPHS 750

__device__ __forceinline__ float sigmoidf_(float x) { return 1.f / (1.f + expf(-x)); }

// ---------------- prep kernels ----------------
__global__ void count_kernel(const int* __restrict__ src, const int* __restrict__ dst,
                             int* __restrict__ cnt, float* __restrict__ deg) {
    int e = blockIdx.x * 256 + threadIdx.x;
    if (e >= N_EDGES) return;
    atomicAdd(&cnt[src[e]], 1);
    atomicAdd(&deg[dst[e]], 1.f);
}

__global__ void scan_kernel(const int* __restrict__ cnt, int* __restrict__ src_ptr,
                            int* __restrict__ cursor) {
    __shared__ int buf[1024];
    __shared__ int carry_s;
    int t = threadIdx.x;
    if (t == 0) carry_s = 0;
    __syncthreads();
    for (int base = 0; base < N_NODES; base += 1024) {
        int carry = carry_s;
        int i = base + t;
        int v = (i < N_NODES) ? cnt[i] : 0;
        buf[t] = v;
        __syncthreads();
        for (int ofs = 1; ofs < 1024; ofs <<= 1) {
            int add = (t >= ofs) ? buf[t - ofs] : 0;
            __syncthreads();
            buf[t] += add;
            __syncthreads();
        }
        int incl = buf[t];
        int excl = incl - v + carry;
        if (i < N_NODES) { src_ptr[i] = excl; cursor[i] = excl; }
        __syncthreads();
        if (t == 1023) carry_s = carry + incl;
        __syncthreads();
    }
    if (t == 0) src_ptr[N_NODES] = carry_s;
}

__global__ void fill_kernel(const int* __restrict__ src, int* __restrict__ cursor,
                            int* __restrict__ edge_list) {
    int e = blockIdx.x * 256 + threadIdx.x;
    if (e >= N_EDGES) return;
    int slot = atomicAdd(&cursor[src[e]], 1);
    edge_list[slot] = e;
}

__global__ void gptr_kernel(const int* __restrict__ batch, int* __restrict__ gptr) {
    int n = blockIdx.x * 256 + threadIdx.x;
    if (n >= N_NODES) return;
    int b = batch[n];
    int pb = (n == 0) ? -1 : batch[n - 1];
    for (int g = pb + 1; g <= b; ++g) gptr[g] = n;
    if (n == N_NODES - 1)
        for (int g = b + 1; g <= N_GRAPHS; ++g) gptr[g] = N_NODES;
}

__global__ void proj_kernel(const float* __restrict__ x, const float* __restrict__ W,
                            const float* __restrict__ b, float* __restrict__ node_h) {
    int idx = blockIdx.x * 256 + threadIdx.x;
    if (idx >= N_NODES * 64) return;
    int n = idx >> 6, f = idx & 63;
    float s = b[f];
    #pragma unroll
    for (int i = 0; i < 32; ++i) s += x[n * 32 + i] * W[i * 64 + f];
    node_h[idx] = fmaxf(s, 0.f);
}

__global__ void h1_kernel(const float* __restrict__ ea, const float* __restrict__ W,
                          const float* __restrict__ b, float* __restrict__ h1) {
    int idx = blockIdx.x * 256 + threadIdx.x;
    if (idx >= N_EDGES * 64) return;
    int e = idx >> 6, f = idx & 63;
    float s = b[f];
    #pragma unroll
    for (int i = 0; i < 16; ++i) s += ea[e * 16 + i] * W[i * 64 + f];
    h1[idx] = fmaxf(s, 0.f);
}

// Pack e2_W (loop-invariant) into coalesced per-lane stream layout:
// Bp4[(ft*64 + d)*128 + pp] = float4 e2W[k = pp>>1][d*64 + ft*8 + (pp&1)*4 .. +3]
__global__ void pack_kernel(const float* __restrict__ e2W, float4* __restrict__ Bp4) {
    int idx = blockIdx.x * 256 + threadIdx.x;  // 8*64*128 = 65536 float4s
    if (idx >= 8 * 64 * 128) return;
    int pp = idx & 127, d = (idx >> 7) & 63, ft = idx >> 13;
    int k = pp >> 1, fo = (pp & 1) * 4;
    Bp4[idx] = *(const float4*)(e2W + (size_t)k * 4096 + d * 64 + ft * 8 + fo);
}

// ---------------- fused conv: per-node T-tile + flat message scatter ----------------
// Grid: 938 node-tiles (16 nodes) x 8 f-tiles (8 f). Block 256 threads.
// Phase A: T[n,fi,k] = sum_d node_h[n,d]*e2W[k, d*64+f0+fi] into LDS (reg tile 8n x 4f).
//          B read from pre-packed Bp (fully coalesced, 1KB/wave-instr).
// Phase B: flat loop over the tile's contiguous out-edge range; nn = src[e]-n0;
//          msg = Tb + dot64(h1[e,:], T[nn,fi,:]) via ds_read_b128; atomicAdd -> agg.
__global__ __launch_bounds__(256, 4)
void conv_kernel(const float* __restrict__ node_h, const float* __restrict__ h1,
                 const float4* __restrict__ Bp4, const float* __restrict__ e2b,
                 const int* __restrict__ src_ptr, const int* __restrict__ edge_list,
                 const int* __restrict__ src, const int* __restrict__ dst,
                 float* __restrict__ agg) {
    __shared__ float T_lds[16][8][68];   // [node][fi][k], k-row padded 64->68
    __shared__ float Tb[16][8];          // bias term: sum_d node_h[n,d]*e2b[d*64+f]
    int bid = blockIdx.x;
    int nt = bid >> 3, ft = bid & 7;
    int n0 = nt * 16, f0 = ft * 8;
    int tid = threadIdx.x;
    int pn = tid >> 7;                   // node half (0/1)
    int pp = tid & 127;
    int k = pp >> 1;
    int fo = (pp & 1) * 4;               // this thread's 4 f's within the 8-wide tile
    int nb = n0 + pn * 8;
    const float4* Bp = Bp4 + (size_t)(ft * 64) * 128 + pp;

    float acc[8][4];
    #pragma unroll
    for (int a = 0; a < 8; ++a)
        #pragma unroll
        for (int b = 0; b < 4; ++b) acc[a][b] = 0.f;

    for (int d4 = 0; d4 < 64; d4 += 4) {
        float4 A[8];
        #pragma unroll
        for (int nn = 0; nn < 8; ++nn) {
            int n = nb + nn;
            A[nn] = (n < N_NODES) ? *(const float4*)(node_h + (size_t)n * 64 + d4)
                                  : make_float4(0.f, 0.f, 0.f, 0.f);
        }
        #pragma unroll
        for (int dd = 0; dd < 4; ++dd) {
            float4 b4 = Bp[(size_t)(d4 + dd) * 128];
            float bv[4] = {b4.x, b4.y, b4.z, b4.w};
            #pragma unroll
            for (int nn = 0; nn < 8; ++nn) {
                float a = (&A[nn].x)[dd];
                #pragma unroll
                for (int j = 0; j < 4; ++j) acc[nn][j] += a * bv[j];
            }
        }
    }
    #pragma unroll
    for (int nn = 0; nn < 8; ++nn)
        #pragma unroll
        for (int j = 0; j < 4; ++j)
            T_lds[pn * 8 + nn][fo + j][k] = acc[nn][j];
    if (tid < 128) {  // 16 nodes x 8 f bias terms
        int nn = tid >> 3, fi = tid & 7;
        int n = n0 + nn;
        float s = 0.f;
        if (n < N_NODES) {
            for (int d = 0; d < 64; ++d) s += node_h[(size_t)n * 64 + d] * e2b[d * 64 + f0 + fi];
        }
        Tb[nn][fi] = s;
    }
    __syncthreads();

    // Phase B: flat edge range for the whole 16-node tile (edge_list grouped by src)
    int fi = tid & 7, slot = tid >> 3;   // 32 edge slots x 8 f
    int nhi = n0 + 16; if (nhi > N_NODES) nhi = N_NODES;
    int te = src_ptr[nhi];
    for (int c = src_ptr[n0] + slot; c < te; c += 32) {
        int e = edge_list[c];
        int nn = src[e] - n0;
        const float* h1e = h1 + (size_t)e * 64;
        const float* Tr = T_lds[nn][fi];
        float s = Tb[nn][fi];
        #pragma unroll
        for (int k4 = 0; k4 < 64; k4 += 4) {
            float4 h4 = *(const float4*)(h1e + k4);
            float4 tv = *(const float4*)(Tr + k4);
            s += h4.x * tv.x + h4.y * tv.y + h4.z * tv.z + h4.w * tv.w;
        }
        atomicAdd(&agg[(size_t)dst[e] * 64 + f0 + fi], s);
    }
}

// ---------------- GRU: weights register-resident, one node per block-iter ----------------
__global__ __launch_bounds__(192)
void gru_kernel(float* __restrict__ node_h, const float* __restrict__ agg,
                const float* __restrict__ deg, const float* __restrict__ conv_b,
                const float* __restrict__ Wih, const float* __restrict__ Whh,
                const float* __restrict__ bih, const float* __restrict__ bhh) {
    __shared__ float m_s[64], h_s[64], gi_s[192], gh_s[192];
    int j = threadIdx.x;  // 0..191 (gate-row)
    float wih[64], whh[64];
    #pragma unroll
    for (int i = 0; i < 64; i += 4) {
        float4 a = *(const float4*)(Wih + (size_t)j * 64 + i);
        wih[i] = a.x; wih[i + 1] = a.y; wih[i + 2] = a.z; wih[i + 3] = a.w;
        float4 c = *(const float4*)(Whh + (size_t)j * 64 + i);
        whh[i] = c.x; whh[i + 1] = c.y; whh[i + 2] = c.z; whh[i + 3] = c.w;
    }
    float bi = bih[j], bh = bhh[j];
    for (int n = blockIdx.x; n < N_NODES; n += gridDim.x) {
        if (j < 64) {
            float dg = fmaxf(deg[n], 1.f);
            m_s[j] = fmaxf(agg[(size_t)n * 64 + j] / dg + conv_b[j], 0.f);
            h_s[j] = node_h[(size_t)n * 64 + j];
        }
        __syncthreads();
        float gi = bi, gh = bh;
        #pragma unroll
        for (int d = 0; d < 64; ++d) { gi += m_s[d] * wih[d]; gh += h_s[d] * whh[d]; }
        gi_s[j] = gi; gh_s[j] = gh;
        __syncthreads();
        if (j < 64) {
            float r = sigmoidf_(gi_s[j] + gh_s[j]);
            float z = sigmoidf_(gi_s[j + 64] + gh_s[j + 64]);
            float nn = tanhf(gi_s[j + 128] + r * gh_s[j + 128]);
            node_h[(size_t)n * 64 + j] = (1.f - z) * nn + z * h_s[j];
        }
        __syncthreads();
    }
}

// ---------------- Set2Set step: LSTM + online-softmax attention, block per graph ----------------
__global__ __launch_bounds__(64)
void s2s_kernel(const float* __restrict__ node_h, const int* __restrict__ gptr,
                float* __restrict__ hl, float* __restrict__ cl, float* __restrict__ q_star,
                const float* __restrict__ Wih, const float* __restrict__ Whh,
                const float* __restrict__ bih, const float* __restrict__ bhh) {
    int g = blockIdx.x, t = threadIdx.x;
    __shared__ float qs[128], hs[64], q[64], wts[64];
    qs[t] = q_star[g * 128 + t];
    qs[64 + t] = q_star[g * 128 + 64 + t];
    hs[t] = hl[g * 64 + t];
    __syncthreads();
    float gv[4];
    #pragma unroll
    for (int gate = 0; gate < 4; ++gate) {
        int row = gate * 64 + t;
        float s = bih[row] + bhh[row];
        const float* wi = Wih + (size_t)row * 128;
        #pragma unroll 8
        for (int i = 0; i < 128; ++i) s += qs[i] * wi[i];
        const float* wh = Whh + (size_t)row * 64;
        #pragma unroll 8
        for (int i = 0; i < 64; ++i) s += hs[i] * wh[i];
        gv[gate] = s;
    }
    float c = sigmoidf_(gv[1]) * cl[g * 64 + t] + sigmoidf_(gv[0]) * tanhf(gv[2]);
    float hn = sigmoidf_(gv[3]) * tanhf(c);
    cl[g * 64 + t] = c;
    hl[g * 64 + t] = hn;
    q[t] = hn;
    __syncthreads();
    int nbeg = gptr[g], nend = gptr[g + 1];
    float rm = -INFINITY, rs = 0.f, racc = 0.f;
    for (int base = nbeg; base < nend; base += 64) {
        int n = base + t;
        float e = -INFINITY;
        if (n < nend) {
            float s = 0.f;
            #pragma unroll 8
            for (int f = 0; f < 64; ++f) s += node_h[(size_t)n * 64 + f] * q[f];
            e = s;
        }
        float cm = e;
        #pragma unroll
        for (int o = 32; o > 0; o >>= 1) cm = fmaxf(cm, __shfl_down(cm, o));
        cm = __shfl(cm, 0);
        float nm = fmaxf(rm, cm);
        float scale = (rm == -INFINITY) ? 0.f : expf(rm - nm);
        float wv = (n < nend) ? expf(e - nm) : 0.f;
        float cs = wv;
        #pragma unroll
        for (int o = 32; o > 0; o >>= 1) cs += __shfl_down(cs, o);
        cs = __shfl(cs, 0);
        wts[t] = wv;
        __syncthreads();
        float na = racc * scale;
        int cnt2 = min(64, nend - base);
        for (int l = 0; l < cnt2; ++l) na += wts[l] * node_h[(size_t)(base + l) * 64 + t];
        racc = na;
        rs = rs * scale + cs;
        rm = nm;
        __syncthreads();
    }
    float r = (nend > nbeg) ? racc / rs : 0.f;
    q_star[g * 128 + t] = q[t];
    q_star[g * 128 + 64 + t] = r;
}

// ---------------- output MLP ----------------
__global__ __launch_bounds__(128)
void out_kernel(const float* __restrict__ q_star, const float* __restrict__ W1,
                const float* __restrict__ b1, const float* __restrict__ W2,
                const float* __restrict__ b2, float* __restrict__ z) {
    int g = blockIdx.x, j = threadIdx.x;
    __shared__ float qs[128], red[128];
    qs[j] = q_star[g * 128 + j];
    __syncthreads();
    float s = b1[j];
    #pragma unroll 8
    for (int i = 0; i < 128; ++i) s += qs[i] * W1[i * 128 + j];
    red[j] = fmaxf(s, 0.f) * W2[j];
    __syncthreads();
    for (int o = 64; o > 0; o >>= 1) {
        if (j < o) red[j] += red[j + o];
        __syncthreads();
    }
    if (j == 0) z[g] = red[0] + b2[0];
}

extern "C" void kernel_launch(void* const* d_in, const int* in_sizes, int n_in,
                              void* d_out, int out_size, void* d_ws, size_t ws_size,
                              hipStream_t stream) {
    const float* x         = (const float*)d_in[0];
    const float* edge_attr = (const float*)d_in[1];
    const int*   ei        = (const int*)d_in[2];
    const int*   batch     = (const int*)d_in[3];
    const float* in_W      = (const float*)d_in[4];
    const float* in_b      = (const float*)d_in[5];
    const float* e1_W      = (const float*)d_in[6];
    const float* e1_b      = (const float*)d_in[7];
    const float* e2_W      = (const float*)d_in[8];
    const float* e2_b      = (const float*)d_in[9];
    const float* conv_b    = (const float*)d_in[10];
    const float* gWih      = (const float*)d_in[11];
    const float* gWhh      = (const float*)d_in[12];
    const float* gbih      = (const float*)d_in[13];
    const float* gbhh      = (const float*)d_in[14];
    const float* lWih      = (const float*)d_in[15];
    const float* lWhh      = (const float*)d_in[16];
    const float* lbih      = (const float*)d_in[17];
    const float* lbhh      = (const float*)d_in[18];
    const float* o1W       = (const float*)d_in[19];
    const float* o1b       = (const float*)d_in[20];
    const float* o2W       = (const float*)d_in[21];
    const float* o2b       = (const float*)d_in[22];
    const int* src = ei;
    const int* dst = ei + N_EDGES;
    float* z = (float*)d_out;

    char* ws = (char*)d_ws;
    size_t off = 0;
    auto alloc = [&](size_t bytes) {
        void* p = ws + off;
        off = (off + bytes + 255) & ~(size_t)255;
        return p;
    };
    float* node_h   = (float*)alloc((size_t)N_NODES * 64 * 4);
    float* agg      = (float*)alloc((size_t)N_NODES * 64 * 4);
    float* h1       = (float*)alloc((size_t)N_EDGES * 64 * 4);
    float* Bp       = (float*)alloc((size_t)8 * 64 * 128 * 4 * 4);   // packed e2_W, 1 MB
    float* deg      = (float*)alloc(N_NODES * 4);       // deg,cnt adjacent (one memset)
    int*   cnt      = (int*)alloc(N_NODES * 4);
    int*   cursor   = (int*)alloc(N_NODES * 4);
    int*   src_ptr  = (int*)alloc((N_NODES + 1) * 4);
    int*   edge_list= (int*)alloc(N_EDGES * 4);
    int*   gptr     = (int*)alloc((N_GRAPHS + 1) * 4);
    float* hl       = (float*)alloc(N_GRAPHS * 64 * 4); // hl,cl,q_star adjacent (one memset)
    float* cl       = (float*)alloc(N_GRAPHS * 64 * 4);
    float* q_star   = (float*)alloc(N_GRAPHS * 128 * 4);

    size_t degpad = ((size_t)N_NODES * 4 + 255) & ~(size_t)255;
    hipMemsetAsync(deg, 0, degpad + (size_t)N_NODES * 4, stream);           // deg + cnt
    hipMemsetAsync(hl, 0, (size_t)N_GRAPHS * (64 + 64 + 128) * 4, stream);  // hl + cl + q_star

    count_kernel<<<(N_EDGES + 255) / 256, 256, 0, stream>>>(src, dst, cnt, deg);
    scan_kernel<<<1, 1024, 0, stream>>>(cnt, src_ptr, cursor);
    fill_kernel<<<(N_EDGES + 255) / 256, 256, 0, stream>>>(src, cursor, edge_list);
    gptr_kernel<<<(N_NODES + 255) / 256, 256, 0, stream>>>(batch, gptr);
    proj_kernel<<<(N_NODES * 64 + 255) / 256, 256, 0, stream>>>(x, in_W, in_b, node_h);
    h1_kernel<<<(N_EDGES * 64 + 255) / 256, 256, 0, stream>>>(edge_attr, e1_W, e1_b, h1);
    pack_kernel<<<256, 256, 0, stream>>>(e2_W, (float4*)Bp);

    for (int it = 0; it < 3; ++it) {
        hipMemsetAsync(agg, 0, (size_t)N_NODES * 64 * 4, stream);
        conv_kernel<<<938 * 8, 256, 0, stream>>>(node_h, h1, (const float4*)Bp, e2_b,
                                                 src_ptr, edge_list, src, dst, agg);
        gru_kernel<<<512, 192, 0, stream>>>(node_h, agg, deg, conv_b, gWih, gWhh, gbih, gbhh);
    }
    for (int st = 0; st < 3; ++st)
        s2s_kernel<<<N_GRAPHS, 64, 0, stream>>>(node_h, gptr, hl, cl, q_star,
                                                lWih, lWhh, lbih, lbhh);
    out_kernel<<<N_GRAPHS, 128, 0, stream>>>(q_star, o1W, o1b, o2W, o2b, z);
}

// Round 3
// 756.642 us; speedup vs baseline: 2.7048x; 1.6466x over previous
//
#include <hip/hip_runtime.h>
#include <math.h>

#define N_NODES 15000
#define N_EDGES 40000
#define N_GRAPHS 750
#define N_TILES 938   // ceil(15000/16)

__device__ __forceinline__ float sigmoidf_(float x) { return 1.f / (1.f + expf(-x)); }

// ---------------- prep kernels ----------------
__global__ void count_kernel(const int* __restrict__ src, const int* __restrict__ dst,
                             int* __restrict__ tcnt, float* __restrict__ deg) {
    int e = blockIdx.x * 256 + threadIdx.x;
    if (e >= N_EDGES) return;
    atomicAdd(&tcnt[src[e] >> 4], 1);
    atomicAdd(&deg[dst[e]], 1.f);
}

// single-round scan over 938 tile counts
__global__ void tscan_kernel(const int* __restrict__ tcnt, int* __restrict__ tptr,
                             int* __restrict__ cursor) {
    __shared__ int buf[1024];
    int t = threadIdx.x;
    int v = (t < N_TILES) ? tcnt[t] : 0;
    buf[t] = v;
    __syncthreads();
    for (int ofs = 1; ofs < 1024; ofs <<= 1) {
        int a = (t >= ofs) ? buf[t - ofs] : 0;
        __syncthreads();
        buf[t] += a;
        __syncthreads();
    }
    if (t < N_TILES) {
        int excl = buf[t] - v;
        tptr[t] = excl;
        cursor[t] = excl;
    }
    if (t == N_TILES - 1) tptr[N_TILES] = buf[t];
}

__global__ void fill_kernel(const int* __restrict__ src, int* __restrict__ cursor,
                            int* __restrict__ edge_list) {
    int e = blockIdx.x * 256 + threadIdx.x;
    if (e >= N_EDGES) return;
    int slot = atomicAdd(&cursor[src[e] >> 4], 1);
    edge_list[slot] = e;
}

__global__ void gptr_kernel(const int* __restrict__ batch, int* __restrict__ gptr) {
    int n = blockIdx.x * 256 + threadIdx.x;
    if (n >= N_NODES) return;
    int b = batch[n];
    int pb = (n == 0) ? -1 : batch[n - 1];
    for (int g = pb + 1; g <= b; ++g) gptr[g] = n;
    if (n == N_NODES - 1)
        for (int g = b + 1; g <= N_GRAPHS; ++g) gptr[g] = N_NODES;
}

__global__ void proj_kernel(const float* __restrict__ x, const float* __restrict__ W,
                            const float* __restrict__ b, float* __restrict__ node_h) {
    int idx = blockIdx.x * 256 + threadIdx.x;
    if (idx >= N_NODES * 64) return;
    int n = idx >> 6, f = idx & 63;
    float s = b[f];
    #pragma unroll
    for (int i = 0; i < 32; ++i) s += x[n * 32 + i] * W[i * 64 + f];
    node_h[idx] = fmaxf(s, 0.f);
}

__global__ void h1_kernel(const float* __restrict__ ea, const float* __restrict__ W,
                          const float* __restrict__ b, float* __restrict__ h1) {
    int idx = blockIdx.x * 256 + threadIdx.x;
    if (idx >= N_EDGES * 64) return;
    int e = idx >> 6, f = idx & 63;
    float s = b[f];
    #pragma unroll
    for (int i = 0; i < 16; ++i) s += ea[e * 16 + i] * W[i * 64 + f];
    h1[idx] = fmaxf(s, 0.f);
}

// Pack e2_W (loop-invariant) into coalesced per-lane stream layout:
// Bp4[(ft*64 + d)*128 + pp] = float4 e2W[k = pp>>1][d*64 + ft*8 + (pp&1)*4 .. +3]
__global__ void pack_kernel(const float* __restrict__ e2W, float4* __restrict__ Bp4) {
    int idx = blockIdx.x * 256 + threadIdx.x;  // 8*64*128 = 65536 float4s
    if (idx >= 8 * 64 * 128) return;
    int pp = idx & 127, d = (idx >> 7) & 63, ft = idx >> 13;
    int k = pp >> 1, fo = (pp & 1) * 4;
    Bp4[idx] = *(const float4*)(e2W + (size_t)k * 4096 + d * 64 + ft * 8 + fo);
}

// Tb[n,f] = sum_d node_h[n,d] * e2b[d*64+f]  (bias term of the conv messages)
__global__ __launch_bounds__(256)
void tb_kernel(const float* __restrict__ node_h, const float* __restrict__ e2b,
               float* __restrict__ Tb_g) {
    __shared__ float hrow[4][64];
    int nb = blockIdx.x * 4;             // 3750 blocks, 4 nodes each (15000 exact)
    int tid = threadIdx.x;
    int nn = tid >> 6, f = tid & 63;
    hrow[nn][f] = node_h[(size_t)(nb + nn) * 64 + f];
    __syncthreads();
    float s = 0.f;
    #pragma unroll 8
    for (int d = 0; d < 64; ++d) s += hrow[nn][d] * e2b[d * 64 + f];
    Tb_g[(size_t)(nb + nn) * 64 + f] = s;
}

// ---------------- fused conv: per-node T-tile + flat message scatter ----------------
// Grid: 938 node-tiles (16 nodes) x 8 f-tiles (8 f). Block 256 threads.
// Phase A: T[n,fi,k] = sum_d A_s[n,d]*e2W[k, d*64+f0+fi]; A staged in LDS (broadcast
//          ds_read_b128), Bp double-buffered in registers (only VMEM in the loop).
// Phase B: flat loop over the tile's edge range; nn = src[e]-n0;
//          msg = Tb + dot64(h1[e,:], T[nn,fi,:]) via ds_read_b128; atomicAdd -> agg.
__global__ __launch_bounds__(256, 4)
void conv_kernel(const float* __restrict__ node_h, const float* __restrict__ h1,
                 const float4* __restrict__ Bp4, const float* __restrict__ Tb_g,
                 const int* __restrict__ tptr, const int* __restrict__ edge_list,
                 const int* __restrict__ src, const int* __restrict__ dst,
                 float* __restrict__ agg) {
    __shared__ float A_s[16][64];        // staged node rows (broadcast-read)
    __shared__ float T_lds[16][8][68];   // [node][fi][k], k-row padded 64->68
    __shared__ float Tb_s[16][8];
    int bid = blockIdx.x;
    int nt = bid >> 3, ft = bid & 3 + 0; // placeholder, fixed below
    nt = bid >> 3; ft = bid & 7;
    int n0 = nt * 16, f0 = ft * 8;
    int tid = threadIdx.x;

    {   // stage A-tile: one float4 per thread, coalesced
        int nn = tid >> 4, d4 = (tid & 15) * 4;
        int n = n0 + nn;
        int nc = (n < N_NODES) ? n : (N_NODES - 1);
        float4 v = *(const float4*)(node_h + (size_t)nc * 64 + d4);
        if (n >= N_NODES) v = make_float4(0.f, 0.f, 0.f, 0.f);
        *(float4*)(&A_s[nn][d4]) = v;
    }
    if (tid < 128) {  // stage Tb
        int nn = tid >> 3, fi = tid & 7;
        int n = n0 + nn;
        Tb_s[nn][fi] = (n < N_NODES) ? Tb_g[(size_t)n * 64 + f0 + fi] : 0.f;
    }
    __syncthreads();

    int pn = tid >> 7;                   // node half (0/1)
    int pp = tid & 127;
    int k = pp >> 1;
    int fo = (pp & 1) * 4;
    int nb = pn * 8;
    const float4* BpP = Bp4 + (size_t)(ft * 64) * 128 + pp;

    float acc[8][4];
    #pragma unroll
    for (int a = 0; a < 8; ++a)
        #pragma unroll
        for (int b = 0; b < 4; ++b) acc[a][b] = 0.f;

    float4 bpre[4];
    #pragma unroll
    for (int dd = 0; dd < 4; ++dd) bpre[dd] = BpP[(size_t)dd * 128];

    for (int d4 = 0; d4 < 64; d4 += 4) {
        float4 bcur[4];
        #pragma unroll
        for (int dd = 0; dd < 4; ++dd) bcur[dd] = bpre[dd];
        if (d4 < 60) {
            #pragma unroll
            for (int dd = 0; dd < 4; ++dd) bpre[dd] = BpP[(size_t)(d4 + 4 + dd) * 128];
        }
        float4 A8[8];
        #pragma unroll
        for (int nn = 0; nn < 8; ++nn) A8[nn] = *(const float4*)(&A_s[nb + nn][d4]);
        #pragma unroll
        for (int dd = 0; dd < 4; ++dd) {
            float bv[4] = {bcur[dd].x, bcur[dd].y, bcur[dd].z, bcur[dd].w};
            #pragma unroll
            for (int nn = 0; nn < 8; ++nn) {
                float a = (&A8[nn].x)[dd];
                #pragma unroll
                for (int j = 0; j < 4; ++j) acc[nn][j] += a * bv[j];
            }
        }
    }
    #pragma unroll
    for (int nn = 0; nn < 8; ++nn)
        #pragma unroll
        for (int j = 0; j < 4; ++j)
            T_lds[pn * 8 + nn][fo + j][k] = acc[nn][j];
    __syncthreads();

    // Phase B: flat edge range for the whole 16-node tile
    int fi = tid & 7, slot = tid >> 3;   // 32 edge slots x 8 f
    int te0 = tptr[nt], te1 = tptr[nt + 1];
    for (int c = te0 + slot; c < te1; c += 32) {
        int e = edge_list[c];
        int nn = src[e] - n0;
        const float* h1e = h1 + (size_t)e * 64;
        const float* Tr = T_lds[nn][fi];
        float s = Tb_s[nn][fi];
        #pragma unroll
        for (int k4 = 0; k4 < 64; k4 += 4) {
            float4 h4 = *(const float4*)(h1e + k4);
            float4 tv = *(const float4*)(Tr + k4);
            s += h4.x * tv.x + h4.y * tv.y + h4.z * tv.z + h4.w * tv.w;
        }
        atomicAdd(&agg[(size_t)dst[e] * 64 + f0 + fi], s);
    }
}

// ---------------- GRU: weights register-resident, one node per block-iter ----------------
__global__ __launch_bounds__(192)
void gru_kernel(float* __restrict__ node_h, const float* __restrict__ agg,
                const float* __restrict__ deg, const float* __restrict__ conv_b,
                const float* __restrict__ Wih, const float* __restrict__ Whh,
                const float* __restrict__ bih, const float* __restrict__ bhh) {
    __shared__ float m_s[64], h_s[64], gi_s[192], gh_s[192];
    int j = threadIdx.x;  // 0..191 (gate-row)
    float wih[64], whh[64];
    #pragma unroll
    for (int i = 0; i < 64; i += 4) {
        float4 a = *(const float4*)(Wih + (size_t)j * 64 + i);
        wih[i] = a.x; wih[i + 1] = a.y; wih[i + 2] = a.z; wih[i + 3] = a.w;
        float4 c = *(const float4*)(Whh + (size_t)j * 64 + i);
        whh[i] = c.x; whh[i + 1] = c.y; whh[i + 2] = c.z; whh[i + 3] = c.w;
    }
    float bi = bih[j], bh = bhh[j];
    for (int n = blockIdx.x; n < N_NODES; n += gridDim.x) {
        if (j < 64) {
            float dg = fmaxf(deg[n], 1.f);
            m_s[j] = fmaxf(agg[(size_t)n * 64 + j] / dg + conv_b[j], 0.f);
            h_s[j] = node_h[(size_t)n * 64 + j];
        }
        __syncthreads();
        float gi = bi, gh = bh;
        #pragma unroll
        for (int d = 0; d < 64; ++d) { gi += m_s[d] * wih[d]; gh += h_s[d] * whh[d]; }
        gi_s[j] = gi; gh_s[j] = gh;
        __syncthreads();
        if (j < 64) {
            float r = sigmoidf_(gi_s[j] + gh_s[j]);
            float z = sigmoidf_(gi_s[j + 64] + gh_s[j + 64]);
            float nn = tanhf(gi_s[j + 128] + r * gh_s[j + 128]);
            node_h[(size_t)n * 64 + j] = (1.f - z) * nn + z * h_s[j];
        }
        __syncthreads();
    }
}

// ---------------- Set2Set step: LSTM + online-softmax attention, block per graph ----------------
__global__ __launch_bounds__(64)
void s2s_kernel(const float* __restrict__ node_h, const int* __restrict__ gptr,
                float* __restrict__ hl, float* __restrict__ cl, float* __restrict__ q_star,
                const float* __restrict__ Wih, const float* __restrict__ Whh,
                const float* __restrict__ bih, const float* __restrict__ bhh) {
    int g = blockIdx.x, t = threadIdx.x;
    __shared__ float qs[128], hs[64], q[64], wts[64];
    qs[t] = q_star[g * 128 + t];
    qs[64 + t] = q_star[g * 128 + 64 + t];
    hs[t] = hl[g * 64 + t];
    __syncthreads();
    float gv[4];
    #pragma unroll
    for (int gate = 0; gate < 4; ++gate) {
        int row = gate * 64 + t;
        float s = bih[row] + bhh[row];
        const float* wi = Wih + (size_t)row * 128;
        #pragma unroll 8
        for (int i = 0; i < 128; ++i) s += qs[i] * wi[i];
        const float* wh = Whh + (size_t)row * 64;
        #pragma unroll 8
        for (int i = 0; i < 64; ++i) s += hs[i] * wh[i];
        gv[gate] = s;
    }
    float c = sigmoidf_(gv[1]) * cl[g * 64 + t] + sigmoidf_(gv[0]) * tanhf(gv[2]);
    float hn = sigmoidf_(gv[3]) * tanhf(c);
    cl[g * 64 + t] = c;
    hl[g * 64 + t] = hn;
    q[t] = hn;
    __syncthreads();
    int nbeg = gptr[g], nend = gptr[g + 1];
    float rm = -INFINITY, rs = 0.f, racc = 0.f;
    for (int base = nbeg; base < nend; base += 64) {
        int n = base + t;
        float e = -INFINITY;
        if (n < nend) {
            float s = 0.f;
            #pragma unroll 8
            for (int f = 0; f < 64; ++f) s += node_h[(size_t)n * 64 + f] * q[f];
            e = s;
        }
        float cm = e;
        #pragma unroll
        for (int o = 32; o > 0; o >>= 1) cm = fmaxf(cm, __shfl_down(cm, o));
        cm = __shfl(cm, 0);
        float nm = fmaxf(rm, cm);
        float scale = (rm == -INFINITY) ? 0.f : expf(rm - nm);
        float wv = (n < nend) ? expf(e - nm) : 0.f;
        float cs = wv;
        #pragma unroll
        for (int o = 32; o > 0; o >>= 1) cs += __shfl_down(cs, o);
        cs = __shfl(cs, 0);
        wts[t] = wv;
        __syncthreads();
        float na = racc * scale;
        int cnt2 = min(64, nend - base);
        for (int l = 0; l < cnt2; ++l) na += wts[l] * node_h[(size_t)(base + l) * 64 + t];
        racc = na;
        rs = rs * scale + cs;
        rm = nm;
        __syncthreads();
    }
    float r = (nend > nbeg) ? racc / rs : 0.f;
    q_star[g * 128 + t] = q[t];
    q_star[g * 128 + 64 + t] = r;
}

// ---------------- output MLP ----------------
__global__ __launch_bounds__(128)
void out_kernel(const float* __restrict__ q_star, const float* __restrict__ W1,
                const float* __restrict__ b1, const float* __restrict__ W2,
                const float* __restrict__ b2, float* __restrict__ z) {
    int g = blockIdx.x, j = threadIdx.x;
    __shared__ float qs[128], red[128];
    qs[j] = q_star[g * 128 + j];
    __syncthreads();
    float s = b1[j];
    #pragma unroll 8
    for (int i = 0; i < 128; ++i) s += qs[i] * W1[i * 128 + j];
    red[j] = fmaxf(s, 0.f) * W2[j];
    __syncthreads();
    for (int o = 64; o > 0; o >>= 1) {
        if (j < o) red[j] += red[j + o];
        __syncthreads();
    }
    if (j == 0) z[g] = red[0] + b2[0];
}

extern "C" void kernel_launch(void* const* d_in, const int* in_sizes, int n_in,
                              void* d_out, int out_size, void* d_ws, size_t ws_size,
                              hipStream_t stream) {
    const float* x         = (const float*)d_in[0];
    const float* edge_attr = (const float*)d_in[1];
    const int*   ei        = (const int*)d_in[2];
    const int*   batch     = (const int*)d_in[3];
    const float* in_W      = (const float*)d_in[4];
    const float* in_b      = (const float*)d_in[5];
    const float* e1_W      = (const float*)d_in[6];
    const float* e1_b      = (const float*)d_in[7];
    const float* e2_W      = (const float*)d_in[8];
    const float* e2_b      = (const float*)d_in[9];
    const float* conv_b    = (const float*)d_in[10];
    const float* gWih      = (const float*)d_in[11];
    const float* gWhh      = (const float*)d_in[12];
    const float* gbih      = (const float*)d_in[13];
    const float* gbhh      = (const float*)d_in[14];
    const float* lWih      = (const float*)d_in[15];
    const float* lWhh      = (const float*)d_in[16];
    const float* lbih      = (const float*)d_in[17];
    const float* lbhh      = (const float*)d_in[18];
    const float* o1W       = (const float*)d_in[19];
    const float* o1b       = (const float*)d_in[20];
    const float* o2W       = (const float*)d_in[21];
    const float* o2b       = (const float*)d_in[22];
    const int* src = ei;
    const int* dst = ei + N_EDGES;
    float* z = (float*)d_out;

    char* ws = (char*)d_ws;
    size_t off = 0;
    auto alloc = [&](size_t bytes) {
        void* p = ws + off;
        off = (off + bytes + 255) & ~(size_t)255;
        return p;
    };
    float* node_h   = (float*)alloc((size_t)N_NODES * 64 * 4);
    float* agg      = (float*)alloc((size_t)N_NODES * 64 * 4);
    float* h1       = (float*)alloc((size_t)N_EDGES * 64 * 4);
    float* Bp       = (float*)alloc((size_t)8 * 64 * 128 * 4 * 4);   // packed e2_W, 1 MB
    float* Tb_g     = (float*)alloc((size_t)N_NODES * 64 * 4);
    float* deg      = (float*)alloc(N_NODES * 4);       // deg,tcnt adjacent (one memset)
    int*   tcnt     = (int*)alloc((N_TILES + 2) * 4);
    int*   tcursor  = (int*)alloc((N_TILES + 2) * 4);
    int*   tptr     = (int*)alloc((N_TILES + 1) * 4);
    int*   edge_list= (int*)alloc(N_EDGES * 4);
    int*   gptr     = (int*)alloc((N_GRAPHS + 1) * 4);
    float* hl       = (float*)alloc(N_GRAPHS * 64 * 4); // hl,cl,q_star adjacent (one memset)
    float* cl       = (float*)alloc(N_GRAPHS * 64 * 4);
    float* q_star   = (float*)alloc(N_GRAPHS * 128 * 4);

    size_t degpad = ((size_t)N_NODES * 4 + 255) & ~(size_t)255;
    hipMemsetAsync(deg, 0, degpad + (N_TILES + 2) * 4, stream);             // deg + tcnt
    hipMemsetAsync(hl, 0, (size_t)N_GRAPHS * (64 + 64 + 128) * 4, stream);  // hl + cl + q_star

    count_kernel<<<(N_EDGES + 255) / 256, 256, 0, stream>>>(src, dst, tcnt, deg);
    tscan_kernel<<<1, 1024, 0, stream>>>(tcnt, tptr, tcursor);
    fill_kernel<<<(N_EDGES + 255) / 256, 256, 0, stream>>>(src, tcursor, edge_list);
    gptr_kernel<<<(N_NODES + 255) / 256, 256, 0, stream>>>(batch, gptr);
    proj_kernel<<<(N_NODES * 64 + 255) / 256, 256, 0, stream>>>(x, in_W, in_b, node_h);
    h1_kernel<<<(N_EDGES * 64 + 255) / 256, 256, 0, stream>>>(edge_attr, e1_W, e1_b, h1);
    pack_kernel<<<256, 256, 0, stream>>>(e2_W, (float4*)Bp);
    tb_kernel<<<N_NODES / 4, 256, 0, stream>>>(node_h, e2_b, Tb_g);

    for (int it = 0; it < 3; ++it) {
        hipMemsetAsync(agg, 0, (size_t)N_NODES * 64 * 4, stream);
        conv_kernel<<<N_TILES * 8, 256, 0, stream>>>(node_h, h1, (const float4*)Bp, Tb_g,
                                                     tptr, edge_list, src, dst, agg);
        gru_kernel<<<512, 192, 0, stream>>>(node_h, agg, deg, conv_b, gWih, gWhh, gbih, gbhh);
        if (it < 2)
            tb_kernel<<<N_NODES / 4, 256, 0, stream>>>(node_h, e2_b, Tb_g);
    }
    for (int st = 0; st < 3; ++st)
        s2s_kernel<<<N_GRAPHS, 64, 0, stream>>>(node_h, gptr, hl, cl, q_star,
                                                lWih, lWhh, lbih, lbhh);
    out_kernel<<<N_GRAPHS, 128, 0, stream>>>(q_star, o1W, o1b, o2W, o2b, z);
}